// Round 1
// baseline (456.238 us; speedup 1.0000x reference)
//
#include <hip/hip_runtime.h>

// Fused MHA: B=4, F=2048, D_HIDDEN=1024, H=16, D=64.
// Pipeline: cvt(q,k,v fp32->bf16) ; transpose-cvt weights ; 3x proj GEMM (bf16 MFMA)
//           ; vh per-head transpose ; flash attention ; output GEMM (fp32 out).
// ws usage ~75.5 MB; qh/kh (bf16) parked in d_out (exact fit), overwritten at the end.

typedef unsigned short u16;
typedef __attribute__((ext_vector_type(8))) short short8;
typedef __attribute__((ext_vector_type(4))) float f32x4;

#define LOG2E 1.4426950408889634f

__device__ __forceinline__ u16 f2bf(float x) {  // RNE fp32->bf16 (finite inputs)
  unsigned int u = __float_as_uint(x);
  u += 0x7FFFu + ((u >> 16) & 1u);
  return (u16)(u >> 16);
}

__device__ __forceinline__ void gload16(const void* g, void* l) {
  __builtin_amdgcn_global_load_lds(
      (const __attribute__((address_space(1))) void*)g,
      (__attribute__((address_space(3))) void*)l, 16, 0, 0);
}

__device__ __forceinline__ uint4 pack8(const u16* t) {
  uint4 o;
  o.x = (unsigned)t[0] | ((unsigned)t[1] << 16);
  o.y = (unsigned)t[2] | ((unsigned)t[3] << 16);
  o.z = (unsigned)t[4] | ((unsigned)t[5] << 16);
  o.w = (unsigned)t[6] | ((unsigned)t[7] << 16);
  return o;
}

// ---------- fp32 -> bf16 elementwise, 8 elems/thread ----------
__global__ __launch_bounds__(256) void cvt_f32_bf16(const float* __restrict__ s,
                                                    u16* __restrict__ d, int n8) {
  int i = blockIdx.x * 256 + threadIdx.x;
  if (i >= n8) return;
  const float4* sp = (const float4*)s;
  float4 a = sp[2 * i], b = sp[2 * i + 1];
  uint4 o;
  o.x = (unsigned)f2bf(a.x) | ((unsigned)f2bf(a.y) << 16);
  o.y = (unsigned)f2bf(a.z) | ((unsigned)f2bf(a.w) << 16);
  o.z = (unsigned)f2bf(b.x) | ((unsigned)f2bf(b.y) << 16);
  o.w = (unsigned)f2bf(b.z) | ((unsigned)f2bf(b.w) << 16);
  ((uint4*)d)[i] = o;
}

// ---------- transpose + cvt: W[1024][1024] fp32 -> WT[1024][1024] bf16 ----------
__global__ __launch_bounds__(256) void wtrans(
    const float* __restrict__ w0, const float* __restrict__ w1,
    const float* __restrict__ w2, const float* __restrict__ w3,
    u16* __restrict__ o0, u16* __restrict__ o1,
    u16* __restrict__ o2, u16* __restrict__ o3) {
  const float* W; u16* O;
  switch (blockIdx.z) {
    case 0: W = w0; O = o0; break;
    case 1: W = w1; O = o1; break;
    case 2: W = w2; O = o2; break;
    default: W = w3; O = o3; break;
  }
  __shared__ u16 T[64][72];
  const int t = threadIdx.x, r = t >> 2, seg = t & 3;
  const int k0 = blockIdx.y * 64, n0 = blockIdx.x * 64;
  const float* src = W + (size_t)(k0 + r) * 1024 + n0 + seg * 16;
#pragma unroll
  for (int jj = 0; jj < 4; jj++) {
    float4 f = ((const float4*)src)[jj];
    T[r][seg * 16 + jj * 4 + 0] = f2bf(f.x);
    T[r][seg * 16 + jj * 4 + 1] = f2bf(f.y);
    T[r][seg * 16 + jj * 4 + 2] = f2bf(f.z);
    T[r][seg * 16 + jj * 4 + 3] = f2bf(f.w);
  }
  __syncthreads();
  u16 tmp[16];
#pragma unroll
  for (int j = 0; j < 16; j++) tmp[j] = T[seg * 16 + j][r];
  u16* dst = O + (size_t)(n0 + r) * 1024 + k0 + seg * 16;
  ((uint4*)dst)[0] = pack8(tmp);
  ((uint4*)dst)[1] = pack8(tmp + 8);
}

// ---------- per-head transpose: vh[8192][1024] -> vhT[(b*16+h)*64 + d][2048] ----------
__global__ __launch_bounds__(256) void vtrans(const u16* __restrict__ vh,
                                              u16* __restrict__ vhT) {
  const int bh = blockIdx.y, f0 = blockIdx.x * 64;
  const int b = bh >> 4, h = bh & 15;
  __shared__ u16 T[64][72];
  const int t = threadIdx.x, r = t >> 2, seg = t & 3;
  const u16* src = vh + (size_t)(b * 2048 + f0 + r) * 1024 + h * 64 + seg * 16;
  uint4 v0 = ((const uint4*)src)[0], v1 = ((const uint4*)src)[1];
  *(uint4*)&T[r][seg * 16] = v0;
  *(uint4*)&T[r][seg * 16 + 8] = v1;
  __syncthreads();
  u16 tmp[16];
#pragma unroll
  for (int j = 0; j < 16; j++) tmp[j] = T[seg * 16 + j][r];
  u16* dst = vhT + (size_t)(bh * 64 + r) * 2048 + f0 + seg * 16;
  ((uint4*)dst)[0] = pack8(tmp);
  ((uint4*)dst)[1] = pack8(tmp + 8);
}

// ---------- 128x128x32 bf16 GEMM (m97 structure): C = A[8192x1024] * Bt[1024x1024]^T ----------
// A row-major [M][K], Bt row-major [N][K]. cfp32: fp32 out (no bias) else bf16 out (+bias).
__global__ __launch_bounds__(256) void gemm128(
    const u16* __restrict__ A, const u16* __restrict__ Bt,
    const float* __restrict__ bias, void* __restrict__ Cout, int cfp32) {
  constexpr int K = 1024, N = 1024;
  __shared__ u16 lsA[128 * 32];
  __shared__ u16 lsB[128 * 32];
  const int tid = threadIdx.x;
  const int w = tid >> 6, lane = tid & 63;
  const int l15 = lane & 15, lg = lane >> 4;
  const int m0 = blockIdx.y << 7, n0 = blockIdx.x << 7;
  const int wr = w >> 1, wc = w & 1;

  f32x4 acc[4][4];
#pragma unroll
  for (int i = 0; i < 4; i++)
#pragma unroll
    for (int j = 0; j < 4; j++) acc[i][j] = f32x4{0.f, 0.f, 0.f, 0.f};

  const u16* As = A + (size_t)(m0 + w * 32 + (lane >> 2)) * K + (lane & 3) * 8;
  const u16* Bs = Bt + (size_t)(n0 + w * 32 + (lane >> 2)) * K + (lane & 3) * 8;
  u16* lA = &lsA[(w * 32) * 32];  // wave-uniform LDS base; HW scatters lane*16B
  u16* lB = &lsB[(w * 32) * 32];

  for (int k0 = 0; k0 < K; k0 += 32) {
    gload16(As + k0, lA);
    gload16(As + 16 * K + k0, lA + 16 * 32);
    gload16(Bs + k0, lB);
    gload16(Bs + 16 * K + k0, lB + 16 * 32);
    __syncthreads();
    short8 af[4], bfv[4];
#pragma unroll
    for (int mi = 0; mi < 4; mi++)
      af[mi] = *(const short8*)&lsA[(wr * 64 + mi * 16 + l15) * 32 + lg * 8];
#pragma unroll
    for (int nj = 0; nj < 4; nj++)
      bfv[nj] = *(const short8*)&lsB[(wc * 64 + nj * 16 + l15) * 32 + lg * 8];
#pragma unroll
    for (int mi = 0; mi < 4; mi++)
#pragma unroll
      for (int nj = 0; nj < 4; nj++)
        acc[mi][nj] = __builtin_amdgcn_mfma_f32_16x16x32_bf16(af[mi], bfv[nj],
                                                              acc[mi][nj], 0, 0, 0);
    __syncthreads();
  }

  const int crow = m0 + wr * 64 + lg * 4;
  const int ccol = n0 + wc * 64 + l15;
  if (cfp32) {
    float* C = (float*)Cout;
#pragma unroll
    for (int nj = 0; nj < 4; nj++)
#pragma unroll
      for (int mi = 0; mi < 4; mi++)
#pragma unroll
        for (int r = 0; r < 4; r++)
          C[(size_t)(crow + mi * 16 + r) * N + ccol + nj * 16] = acc[mi][nj][r];
  } else {
    u16* C = (u16*)Cout;
#pragma unroll
    for (int nj = 0; nj < 4; nj++) {
      float bv = bias[ccol + nj * 16];
#pragma unroll
      for (int mi = 0; mi < 4; mi++)
#pragma unroll
        for (int r = 0; r < 4; r++)
          C[(size_t)(crow + mi * 16 + r) * N + ccol + nj * 16] =
              f2bf(acc[mi][nj][r] + bv);
    }
  }
}

// ---------- flash attention ----------
// grid 1024: blk = ((b*16+h)*16 + qtile). 4 waves; wave owns 32 q-rows; KTILE=64.
__global__ __launch_bounds__(256) void attn_fwd(
    const u16* __restrict__ qh, const u16* __restrict__ kh,
    const u16* __restrict__ vhT, const float* __restrict__ mask,
    u16* __restrict__ aout) {
  __shared__ u16 Kls[64][72];   // K-tile  [krow][d]   (+8 pad)
  __shared__ u16 Vls[64][72];   // V^T tile [d][kcol]
  __shared__ u16 Pls[128][72];  // P round-trip, 32 rows per wave

  const int tid = threadIdx.x;
  const int w = tid >> 6, lane = tid & 63;
  const int l15 = lane & 15, lg = lane >> 4;
  const int blk = blockIdx.x;
  const int qt = blk & 15, bh = blk >> 4, h = bh & 15, b = bh >> 4;
  const int frow = qt * 128 + w * 32;              // q row within batch b
  const size_t qrow0 = (size_t)b * 2048 + frow;    // q row in [8192]

  // Q fragments in registers: rows qrow0 + mi*16 + l15, k = kd*32 + lg*8 + j
  short8 qf[2][2];
#pragma unroll
  for (int mi = 0; mi < 2; mi++)
#pragma unroll
    for (int kd = 0; kd < 2; kd++)
      qf[mi][kd] = *(const short8*)&qh[(qrow0 + mi * 16 + l15) * 1024 +
                                       h * 64 + kd * 32 + lg * 8];

  f32x4 oacc[2][4];
  float m_run[2][4], l_run[2][4];
#pragma unroll
  for (int mi = 0; mi < 2; mi++) {
#pragma unroll
    for (int dj = 0; dj < 4; dj++) oacc[mi][dj] = f32x4{0.f, 0.f, 0.f, 0.f};
#pragma unroll
    for (int r = 0; r < 4; r++) { m_run[mi][r] = -1e30f; l_run[mi][r] = 0.f; }
  }

  const int sr = tid >> 2, seg = tid & 3;  // staging: row, 16-elem segment
  const u16* Ksrc = kh + ((size_t)b * 2048 + sr) * 1024 + h * 64 + seg * 16;
  const u16* Vsrc = vhT + (size_t)(bh * 64 + sr) * 2048 + seg * 16;

  for (int k0 = 0; k0 < 2048; k0 += 64) {
    // ---- stage K/V tiles ----
    {
      const uint4* kp = (const uint4*)(Ksrc + (size_t)k0 * 1024);
      uint4 ka = kp[0], kb = kp[1];
      const uint4* vp = (const uint4*)(Vsrc + k0);
      uint4 va = vp[0], vb = vp[1];
      *(uint4*)&Kls[sr][seg * 16] = ka;
      *(uint4*)&Kls[sr][seg * 16 + 8] = kb;
      *(uint4*)&Vls[sr][seg * 16] = va;
      *(uint4*)&Vls[sr][seg * 16 + 8] = vb;
    }
    __syncthreads();

    // ---- S = Q * K^T ----
    f32x4 sacc[2][4];
#pragma unroll
    for (int mi = 0; mi < 2; mi++)
#pragma unroll
      for (int nj = 0; nj < 4; nj++) sacc[mi][nj] = f32x4{0.f, 0.f, 0.f, 0.f};
    short8 kf[4][2];
#pragma unroll
    for (int nj = 0; nj < 4; nj++)
#pragma unroll
      for (int kd = 0; kd < 2; kd++)
        kf[nj][kd] = *(const short8*)&Kls[nj * 16 + l15][kd * 32 + lg * 8];
#pragma unroll
    for (int mi = 0; mi < 2; mi++)
#pragma unroll
      for (int nj = 0; nj < 4; nj++)
#pragma unroll
        for (int kd = 0; kd < 2; kd++)
          sacc[mi][nj] = __builtin_amdgcn_mfma_f32_16x16x32_bf16(
              qf[mi][kd], kf[nj][kd], sacc[mi][nj], 0, 0, 0);

    // ---- online softmax (fp32) ----
    const size_t mbase = ((size_t)b * 2048 + frow) * 2048 + k0;
#pragma unroll
    for (int mi = 0; mi < 2; mi++) {
      float pv[4][4];
#pragma unroll
      for (int nj = 0; nj < 4; nj++)
#pragma unroll
        for (int r = 0; r < 4; r++) {
          float mv = mask[mbase + (size_t)(mi * 16 + lg * 4 + r) * 2048 +
                          nj * 16 + l15];
          pv[nj][r] = fmaf(mv, -1e9f, sacc[mi][nj][r] * 0.125f);
        }
#pragma unroll
      for (int r = 0; r < 4; r++) {
        float mx = fmaxf(fmaxf(pv[0][r], pv[1][r]), fmaxf(pv[2][r], pv[3][r]));
        mx = fmaxf(mx, __shfl_xor(mx, 1, 64));
        mx = fmaxf(mx, __shfl_xor(mx, 2, 64));
        mx = fmaxf(mx, __shfl_xor(mx, 4, 64));
        mx = fmaxf(mx, __shfl_xor(mx, 8, 64));
        float mold = m_run[mi][r];
        float mnew = fmaxf(mold, mx);
        m_run[mi][r] = mnew;
        float al = exp2f((mold - mnew) * LOG2E);
        float rs = 0.f;
#pragma unroll
        for (int nj = 0; nj < 4; nj++) {
          float p = exp2f((pv[nj][r] - mnew) * LOG2E);
          pv[nj][r] = p;
          rs += p;
        }
        rs += __shfl_xor(rs, 1, 64);
        rs += __shfl_xor(rs, 2, 64);
        rs += __shfl_xor(rs, 4, 64);
        rs += __shfl_xor(rs, 8, 64);
        l_run[mi][r] = l_run[mi][r] * al + rs;
#pragma unroll
        for (int dj = 0; dj < 4; dj++) oacc[mi][dj][r] *= al;
      }
#pragma unroll
      for (int nj = 0; nj < 4; nj++)
#pragma unroll
        for (int r = 0; r < 4; r++)
          Pls[w * 32 + mi * 16 + lg * 4 + r][nj * 16 + l15] = f2bf(pv[nj][r]);
    }

    // ---- O += P * V ----
    short8 pf[2][2], vf[4][2];
#pragma unroll
    for (int mi = 0; mi < 2; mi++)
#pragma unroll
      for (int kk = 0; kk < 2; kk++)
        pf[mi][kk] = *(const short8*)&Pls[w * 32 + mi * 16 + l15][kk * 32 + lg * 8];
#pragma unroll
    for (int dj = 0; dj < 4; dj++)
#pragma unroll
      for (int kk = 0; kk < 2; kk++)
        vf[dj][kk] = *(const short8*)&Vls[dj * 16 + l15][kk * 32 + lg * 8];
#pragma unroll
    for (int mi = 0; mi < 2; mi++)
#pragma unroll
      for (int dj = 0; dj < 4; dj++)
#pragma unroll
        for (int kk = 0; kk < 2; kk++)
          oacc[mi][dj] = __builtin_amdgcn_mfma_f32_16x16x32_bf16(
              pf[mi][kk], vf[dj][kk], oacc[mi][dj], 0, 0, 0);

    __syncthreads();
  }

  // ---- epilogue: O / l ----
#pragma unroll
  for (int mi = 0; mi < 2; mi++)
#pragma unroll
    for (int r = 0; r < 4; r++) {
      float inv = 1.0f / l_run[mi][r];
#pragma unroll
      for (int dj = 0; dj < 4; dj++)
        aout[(qrow0 + mi * 16 + lg * 4 + r) * 1024 + h * 64 + dj * 16 + l15] =
            f2bf(oacc[mi][dj][r] * inv);
    }
}

extern "C" void kernel_launch(void* const* d_in, const int* in_sizes, int n_in,
                              void* d_out, int out_size, void* d_ws, size_t ws_size,
                              hipStream_t stream) {
  (void)in_sizes; (void)n_in; (void)out_size; (void)ws_size;
  const float* q    = (const float*)d_in[0];
  const float* k    = (const float*)d_in[1];
  const float* v    = (const float*)d_in[2];
  const float* mask = (const float*)d_in[3];
  const float* qw_w = (const float*)d_in[4];
  const float* qw_b = (const float*)d_in[5];
  const float* kw_w = (const float*)d_in[6];
  const float* kw_b = (const float*)d_in[7];
  const float* vw_w = (const float*)d_in[8];
  const float* vw_b = (const float*)d_in[9];
  const float* wo   = (const float*)d_in[10];

  // workspace layout (u16 elems); total 75.5 MB
  u16* qbf = (u16*)d_ws;               // 8192*1024
  u16* kbf = qbf + 8192 * 1024;
  u16* vbf = kbf + 8192 * 1024;
  u16* vh  = vbf + 8192 * 1024;
  u16* qwT = vh + 8192 * 1024;         // 4x 1024*1024
  u16* kwT = qwT + 1024 * 1024;
  u16* vwT = kwT + 1024 * 1024;
  u16* woT = vwT + 1024 * 1024;
  u16* vhT    = qbf;                   // reuse after projections
  u16* attn_o = kbf;                   // reuse after projections
  u16* qh = (u16*)d_out;               // park bf16 qh/kh in d_out (exact fit),
  u16* kh = qh + 8192 * 1024;          // overwritten by the final fp32 GEMM

  cvt_f32_bf16<<<4096, 256, 0, stream>>>(q, qbf, 1048576);
  cvt_f32_bf16<<<4096, 256, 0, stream>>>(k, kbf, 1048576);
  cvt_f32_bf16<<<4096, 256, 0, stream>>>(v, vbf, 1048576);
  wtrans<<<dim3(16, 16, 4), 256, 0, stream>>>(qw_w, kw_w, vw_w, wo,
                                              qwT, kwT, vwT, woT);
  gemm128<<<dim3(8, 64), 256, 0, stream>>>(qbf, qwT, qw_b, qh, 0);
  gemm128<<<dim3(8, 64), 256, 0, stream>>>(kbf, kwT, kw_b, kh, 0);
  gemm128<<<dim3(8, 64), 256, 0, stream>>>(vbf, vwT, vw_b, vh, 0);
  vtrans<<<dim3(32, 64), 256, 0, stream>>>(vh, vhT);
  attn_fwd<<<1024, 256, 0, stream>>>(qh, kh, vhT, mask, attn_o);
  gemm128<<<dim3(8, 64), 256, 0, stream>>>(attn_o, woT, nullptr, d_out, 1);
}

// Round 2
// 349.751 us; speedup vs baseline: 1.3045x; 1.3045x over previous
//
#include <hip/hip_runtime.h>

// Fused MHA: B=4, F=2048, D_HIDDEN=1024, H=16, D=64.
// cvt(q,k,v) ; wtrans ; 3x proj GEMM ; vtrans ; masksum ; flash attn (swapped QK^T,
// in-lane softmax, mask fast-path, defer-max, async-stage) ; out GEMM (fp32).
// ws ~75.5 MB; qh/kh (bf16) parked in d_out (exact fit); masksum parked in qwT region.

typedef unsigned short u16;
typedef __attribute__((ext_vector_type(8))) short short8;
typedef __attribute__((ext_vector_type(4))) float f32x4;

#define SC 0.18033688011112042f          // 0.125 * log2(e)
#define MSC -1.4426950408889634e9f       // -1e9 * log2(e)
#define THR 8.0f                         // defer-max threshold (log2 space)

__device__ __forceinline__ u16 f2bf(float x) {  // RNE fp32->bf16 (finite inputs)
  unsigned int u = __float_as_uint(x);
  u += 0x7FFFu + ((u >> 16) & 1u);
  return (u16)(u >> 16);
}

__device__ __forceinline__ void gload16(const void* g, void* l) {
  __builtin_amdgcn_global_load_lds(
      (const __attribute__((address_space(1))) void*)g,
      (__attribute__((address_space(3))) void*)l, 16, 0, 0);
}

__device__ __forceinline__ uint4 pack8(const u16* t) {
  uint4 o;
  o.x = (unsigned)t[0] | ((unsigned)t[1] << 16);
  o.y = (unsigned)t[2] | ((unsigned)t[3] << 16);
  o.z = (unsigned)t[4] | ((unsigned)t[5] << 16);
  o.w = (unsigned)t[6] | ((unsigned)t[7] << 16);
  return o;
}

__device__ __forceinline__ unsigned cvtpk(float lo, float hi) {
  unsigned r;
  asm("v_cvt_pk_bf16_f32 %0, %1, %2" : "=v"(r) : "v"(lo), "v"(hi));
  return r;
}

// ---------- fp32 -> bf16 elementwise, 8 elems/thread ----------
__global__ __launch_bounds__(256) void cvt_f32_bf16(const float* __restrict__ s,
                                                    u16* __restrict__ d, int n8) {
  int i = blockIdx.x * 256 + threadIdx.x;
  if (i >= n8) return;
  const float4* sp = (const float4*)s;
  float4 a = sp[2 * i], b = sp[2 * i + 1];
  uint4 o;
  o.x = (unsigned)f2bf(a.x) | ((unsigned)f2bf(a.y) << 16);
  o.y = (unsigned)f2bf(a.z) | ((unsigned)f2bf(a.w) << 16);
  o.z = (unsigned)f2bf(b.x) | ((unsigned)f2bf(b.y) << 16);
  o.w = (unsigned)f2bf(b.z) | ((unsigned)f2bf(b.w) << 16);
  ((uint4*)d)[i] = o;
}

// ---------- mask summary: msum[b][kt][row] = any(mask[b][row][kt*64 .. +63] != 0) ----------
__global__ __launch_bounds__(256) void masksum(const float* __restrict__ mask,
                                               unsigned char* __restrict__ msum) {
  int t = blockIdx.x * 256 + threadIdx.x;   // t = b*65536 + kt*2048 + row
  int row = t & 2047;
  int kt = (t >> 11) & 31;
  int b = t >> 16;
  const float4* p =
      (const float4*)(mask + ((size_t)(b * 2048 + row)) * 2048 + kt * 64);
  unsigned acc = 0;
#pragma unroll
  for (int i = 0; i < 16; i++) {
    float4 f = p[i];
    acc |= __float_as_uint(f.x) | __float_as_uint(f.y) |
           __float_as_uint(f.z) | __float_as_uint(f.w);
  }
  msum[t] = acc ? 1 : 0;
}

// ---------- transpose + cvt: W[1024][1024] fp32 -> WT[1024][1024] bf16 ----------
__global__ __launch_bounds__(256) void wtrans(
    const float* __restrict__ w0, const float* __restrict__ w1,
    const float* __restrict__ w2, const float* __restrict__ w3,
    u16* __restrict__ o0, u16* __restrict__ o1,
    u16* __restrict__ o2, u16* __restrict__ o3) {
  const float* W; u16* O;
  switch (blockIdx.z) {
    case 0: W = w0; O = o0; break;
    case 1: W = w1; O = o1; break;
    case 2: W = w2; O = o2; break;
    default: W = w3; O = o3; break;
  }
  __shared__ u16 T[64][72];
  const int t = threadIdx.x, r = t >> 2, seg = t & 3;
  const int k0 = blockIdx.y * 64, n0 = blockIdx.x * 64;
  const float* src = W + (size_t)(k0 + r) * 1024 + n0 + seg * 16;
#pragma unroll
  for (int jj = 0; jj < 4; jj++) {
    float4 f = ((const float4*)src)[jj];
    T[r][seg * 16 + jj * 4 + 0] = f2bf(f.x);
    T[r][seg * 16 + jj * 4 + 1] = f2bf(f.y);
    T[r][seg * 16 + jj * 4 + 2] = f2bf(f.z);
    T[r][seg * 16 + jj * 4 + 3] = f2bf(f.w);
  }
  __syncthreads();
  u16 tmp[16];
#pragma unroll
  for (int j = 0; j < 16; j++) tmp[j] = T[seg * 16 + j][r];
  u16* dst = O + (size_t)(n0 + r) * 1024 + k0 + seg * 16;
  ((uint4*)dst)[0] = pack8(tmp);
  ((uint4*)dst)[1] = pack8(tmp + 8);
}

// ---------- per-head transpose: vh[8192][1024] -> vhT[(b*16+h)*64 + d][2048] ----------
__global__ __launch_bounds__(256) void vtrans(const u16* __restrict__ vh,
                                              u16* __restrict__ vhT) {
  const int bh = blockIdx.y, f0 = blockIdx.x * 64;
  const int b = bh >> 4, h = bh & 15;
  __shared__ u16 T[64][72];
  const int t = threadIdx.x, r = t >> 2, seg = t & 3;
  const u16* src = vh + (size_t)(b * 2048 + f0 + r) * 1024 + h * 64 + seg * 16;
  uint4 v0 = ((const uint4*)src)[0], v1 = ((const uint4*)src)[1];
  *(uint4*)&T[r][seg * 16] = v0;
  *(uint4*)&T[r][seg * 16 + 8] = v1;
  __syncthreads();
  u16 tmp[16];
#pragma unroll
  for (int j = 0; j < 16; j++) tmp[j] = T[seg * 16 + j][r];
  u16* dst = vhT + (size_t)(bh * 64 + r) * 2048 + f0 + seg * 16;
  ((uint4*)dst)[0] = pack8(tmp);
  ((uint4*)dst)[1] = pack8(tmp + 8);
}

// ---------- 128x128x32 bf16 GEMM: C = A[8192x1024] * Bt[1024x1024]^T ----------
__global__ __launch_bounds__(256) void gemm128(
    const u16* __restrict__ A, const u16* __restrict__ Bt,
    const float* __restrict__ bias, void* __restrict__ Cout, int cfp32) {
  constexpr int K = 1024, N = 1024;
  __shared__ u16 lsA[128 * 32];
  __shared__ u16 lsB[128 * 32];
  const int tid = threadIdx.x;
  const int w = tid >> 6, lane = tid & 63;
  const int l15 = lane & 15, lg = lane >> 4;
  const int m0 = blockIdx.y << 7, n0 = blockIdx.x << 7;
  const int wr = w >> 1, wc = w & 1;

  f32x4 acc[4][4];
#pragma unroll
  for (int i = 0; i < 4; i++)
#pragma unroll
    for (int j = 0; j < 4; j++) acc[i][j] = f32x4{0.f, 0.f, 0.f, 0.f};

  const u16* As = A + (size_t)(m0 + w * 32 + (lane >> 2)) * K + (lane & 3) * 8;
  const u16* Bs = Bt + (size_t)(n0 + w * 32 + (lane >> 2)) * K + (lane & 3) * 8;
  u16* lA = &lsA[(w * 32) * 32];
  u16* lB = &lsB[(w * 32) * 32];

  for (int k0 = 0; k0 < K; k0 += 32) {
    gload16(As + k0, lA);
    gload16(As + 16 * K + k0, lA + 16 * 32);
    gload16(Bs + k0, lB);
    gload16(Bs + 16 * K + k0, lB + 16 * 32);
    __syncthreads();
    short8 af[4], bfv[4];
#pragma unroll
    for (int mi = 0; mi < 4; mi++)
      af[mi] = *(const short8*)&lsA[(wr * 64 + mi * 16 + l15) * 32 + lg * 8];
#pragma unroll
    for (int nj = 0; nj < 4; nj++)
      bfv[nj] = *(const short8*)&lsB[(wc * 64 + nj * 16 + l15) * 32 + lg * 8];
#pragma unroll
    for (int mi = 0; mi < 4; mi++)
#pragma unroll
      for (int nj = 0; nj < 4; nj++)
        acc[mi][nj] = __builtin_amdgcn_mfma_f32_16x16x32_bf16(af[mi], bfv[nj],
                                                              acc[mi][nj], 0, 0, 0);
    __syncthreads();
  }

  const int crow = m0 + wr * 64 + lg * 4;
  const int ccol = n0 + wc * 64 + l15;
  if (cfp32) {
    float* C = (float*)Cout;
#pragma unroll
    for (int nj = 0; nj < 4; nj++)
#pragma unroll
      for (int mi = 0; mi < 4; mi++)
#pragma unroll
        for (int r = 0; r < 4; r++)
          C[(size_t)(crow + mi * 16 + r) * N + ccol + nj * 16] = acc[mi][nj][r];
  } else {
    u16* C = (u16*)Cout;
#pragma unroll
    for (int nj = 0; nj < 4; nj++) {
      float bv = bias[ccol + nj * 16];
#pragma unroll
      for (int mi = 0; mi < 4; mi++)
#pragma unroll
        for (int r = 0; r < 4; r++)
          C[(size_t)(crow + mi * 16 + r) * N + ccol + nj * 16] =
              f2bf(acc[mi][nj][r] + bv);
    }
  }
}

// ---------- flash attention (swapped QK^T, in-lane softmax) ----------
// grid 1024: blk = ((b*16+h)*16 + qtile). 4 waves; wave owns 32 q-rows; KTILE=64.
__global__ __launch_bounds__(256) void attn_fwd(
    const u16* __restrict__ qh, const u16* __restrict__ kh,
    const u16* __restrict__ vhT, const float* __restrict__ mask,
    const unsigned char* __restrict__ msum, u16* __restrict__ aout) {
  __shared__ u16 Kls[64][72];   // K-tile  [krow][d]
  __shared__ u16 Vls[64][72];   // V^T tile [d][kcol]
  __shared__ u16 Pls[128][72];  // P [q][k], 32 rows per wave (wave-private)

  const int tid = threadIdx.x;
  const int w = tid >> 6, lane = tid & 63;
  const int l15 = lane & 15, lg = lane >> 4;
  const int blk = blockIdx.x;
  const int qt = blk & 15, bh = blk >> 4, h = bh & 15, b = bh >> 4;
  const int frow = qt * 128 + w * 32;            // q row within batch b
  const size_t qrow0 = (size_t)b * 2048 + frow;  // q row in [8192]

  // Q fragments (A-frag layout): rows qrow0 + mi*16 + l15, d = kd*32 + lg*8 + j
  short8 qf[2][2];
#pragma unroll
  for (int mi = 0; mi < 2; mi++)
#pragma unroll
    for (int kd = 0; kd < 2; kd++)
      qf[mi][kd] = *(const short8*)&qh[(qrow0 + mi * 16 + l15) * 1024 +
                                       h * 64 + kd * 32 + lg * 8];

  f32x4 oacc[2][4];
#pragma unroll
  for (int mi = 0; mi < 2; mi++)
#pragma unroll
    for (int dj = 0; dj < 4; dj++) oacc[mi][dj] = f32x4{0.f, 0.f, 0.f, 0.f};
  float m_run[2] = {-1e30f, -1e30f};  // per-lane, q = mi*16 + l15 (l15-space)
  float l_run[2] = {0.f, 0.f};

  const int sr = tid >> 2, seg = tid & 3;  // staging: row, 16-elem segment
  const u16* Ksrc = kh + ((size_t)b * 2048 + sr) * 1024 + h * 64 + seg * 16;
  const u16* Vsrc = vhT + (size_t)(bh * 64 + sr) * 2048 + seg * 16;
  const unsigned char* msrow = msum + (size_t)b * 65536 + frow + (lane & 31);

  // prologue: tile 0 loads into registers (async-stage split, T14)
  uint4 kr0 = ((const uint4*)Ksrc)[0], kr1 = ((const uint4*)Ksrc)[1];
  uint4 vr0 = ((const uint4*)Vsrc)[0], vr1 = ((const uint4*)Vsrc)[1];
  unsigned char mb = msrow[0];

  for (int kt = 0; kt < 32; kt++) {
    const int k0 = kt * 64;
    __syncthreads();  // prev tile's LDS reads complete
    *(uint4*)&Kls[sr][seg * 16] = kr0;
    *(uint4*)&Kls[sr][seg * 16 + 8] = kr1;
    *(uint4*)&Vls[sr][seg * 16] = vr0;
    *(uint4*)&Vls[sr][seg * 16 + 8] = vr1;
    __syncthreads();  // staged

    unsigned char mb_cur = mb;
    if (kt < 31) {  // issue next tile's loads; latency hides under compute
      const uint4* kp = (const uint4*)(Ksrc + (size_t)(k0 + 64) * 1024);
      kr0 = kp[0]; kr1 = kp[1];
      const uint4* vp = (const uint4*)(Vsrc + k0 + 64);
      vr0 = vp[0]; vr1 = vp[1];
      mb = msrow[(size_t)(kt + 1) * 2048];
    }
    const int mflag = __any((int)mb_cur);

    // ---- S^T = K * Q^T : C[k=lg*4+r (+16nj)][q=l15 (+16mi)] ----
    short8 kf[4][2];
#pragma unroll
    for (int nj = 0; nj < 4; nj++)
#pragma unroll
      for (int kd = 0; kd < 2; kd++)
        kf[nj][kd] = *(const short8*)&Kls[nj * 16 + l15][kd * 32 + lg * 8];
    f32x4 sT[2][4];
#pragma unroll
    for (int mi = 0; mi < 2; mi++)
#pragma unroll
      for (int nj = 0; nj < 4; nj++) sT[mi][nj] = f32x4{0.f, 0.f, 0.f, 0.f};
    __builtin_amdgcn_s_setprio(1);
#pragma unroll
    for (int mi = 0; mi < 2; mi++)
#pragma unroll
      for (int nj = 0; nj < 4; nj++)
#pragma unroll
        for (int kd = 0; kd < 2; kd++)
          sT[mi][nj] = __builtin_amdgcn_mfma_f32_16x16x32_bf16(
              kf[nj][kd], qf[mi][kd], sT[mi][nj], 0, 0, 0);
    __builtin_amdgcn_s_setprio(0);

    // ---- softmax: lane owns q = mi*16 + l15, 16 k-values in-lane ----
#pragma unroll
    for (int mi = 0; mi < 2; mi++) {
      float pvv[16];
#pragma unroll
      for (int nj = 0; nj < 4; nj++)
#pragma unroll
        for (int r = 0; r < 4; r++) pvv[nj * 4 + r] = sT[mi][nj][r] * SC;
      if (mflag) {  // rare: apply additive mask
        const size_t mrow =
            ((size_t)b * 2048 + frow + mi * 16 + l15) * 2048 + k0 + lg * 4;
#pragma unroll
        for (int nj = 0; nj < 4; nj++)
#pragma unroll
          for (int r = 0; r < 4; r++)
            pvv[nj * 4 + r] = fmaf(mask[mrow + nj * 16 + r], MSC, pvv[nj * 4 + r]);
      }
      // in-lane max over 16, then reduce across lg groups (xor 16, 32)
      float tm = fmaxf(pvv[0], pvv[1]);
#pragma unroll
      for (int j = 2; j < 16; j++) tm = fmaxf(tm, pvv[j]);
      tm = fmaxf(tm, __shfl_xor(tm, 16, 64));
      tm = fmaxf(tm, __shfl_xor(tm, 32, 64));
      float mold = m_run[mi];
      float al = 1.f;
      if (!__all(tm <= mold + THR)) {  // defer-max: rescale only on real growth
        float mnew = fmaxf(mold, tm);
        al = exp2f(mold - mnew);
        m_run[mi] = mnew;
        float alr[4];
#pragma unroll
        for (int r = 0; r < 4; r++) alr[r] = __shfl(al, lg * 4 + r, 64);
#pragma unroll
        for (int dj = 0; dj < 4; dj++)
#pragma unroll
          for (int r = 0; r < 4; r++) oacc[mi][dj][r] *= alr[r];
      }
      const float mm = m_run[mi];
      float rs = 0.f;
#pragma unroll
      for (int j = 0; j < 16; j++) {
        pvv[j] = exp2f(pvv[j] - mm);
        rs += pvv[j];
      }
      rs += __shfl_xor(rs, 16, 64);
      rs += __shfl_xor(rs, 32, 64);
      l_run[mi] = l_run[mi] * al + rs;
      // pack 4 bf16 along k and store 8B (2-way banks: free)
#pragma unroll
      for (int nj = 0; nj < 4; nj++) {
        uint2 pw;
        pw.x = cvtpk(pvv[nj * 4 + 0], pvv[nj * 4 + 1]);
        pw.y = cvtpk(pvv[nj * 4 + 2], pvv[nj * 4 + 3]);
        *(uint2*)&Pls[w * 32 + mi * 16 + l15][nj * 16 + lg * 4] = pw;
      }
    }

    // ---- O += P * V (standard layout; Pls region is wave-private) ----
    short8 pf[2][2], vf[4][2];
#pragma unroll
    for (int mi = 0; mi < 2; mi++)
#pragma unroll
      for (int kk = 0; kk < 2; kk++)
        pf[mi][kk] =
            *(const short8*)&Pls[w * 32 + mi * 16 + l15][kk * 32 + lg * 8];
#pragma unroll
    for (int dj = 0; dj < 4; dj++)
#pragma unroll
      for (int kk = 0; kk < 2; kk++)
        vf[dj][kk] = *(const short8*)&Vls[dj * 16 + l15][kk * 32 + lg * 8];
    __builtin_amdgcn_s_setprio(1);
#pragma unroll
    for (int mi = 0; mi < 2; mi++)
#pragma unroll
      for (int dj = 0; dj < 4; dj++)
#pragma unroll
        for (int kk = 0; kk < 2; kk++)
          oacc[mi][dj] = __builtin_amdgcn_mfma_f32_16x16x32_bf16(
              pf[mi][kk], vf[dj][kk], oacc[mi][dj], 0, 0, 0);
    __builtin_amdgcn_s_setprio(0);
  }

  // ---- epilogue: O / l (redistribute 1/l from l15-space to row-space) ----
#pragma unroll
  for (int mi = 0; mi < 2; mi++) {
    float inv = 1.0f / l_run[mi];
#pragma unroll
    for (int r = 0; r < 4; r++) {
      float invr = __shfl(inv, lg * 4 + r, 64);
#pragma unroll
      for (int dj = 0; dj < 4; dj++)
        aout[(qrow0 + mi * 16 + lg * 4 + r) * 1024 + h * 64 + dj * 16 + l15] =
            f2bf(oacc[mi][dj][r] * invr);
    }
  }
}

extern "C" void kernel_launch(void* const* d_in, const int* in_sizes, int n_in,
                              void* d_out, int out_size, void* d_ws, size_t ws_size,
                              hipStream_t stream) {
  (void)in_sizes; (void)n_in; (void)out_size; (void)ws_size;
  const float* q    = (const float*)d_in[0];
  const float* k    = (const float*)d_in[1];
  const float* v    = (const float*)d_in[2];
  const float* mask = (const float*)d_in[3];
  const float* qw_w = (const float*)d_in[4];
  const float* qw_b = (const float*)d_in[5];
  const float* kw_w = (const float*)d_in[6];
  const float* kw_b = (const float*)d_in[7];
  const float* vw_w = (const float*)d_in[8];
  const float* vw_b = (const float*)d_in[9];
  const float* wo   = (const float*)d_in[10];

  // workspace layout (u16 elems); total 75.5 MB
  u16* qbf = (u16*)d_ws;               // 8192*1024
  u16* kbf = qbf + 8192 * 1024;
  u16* vbf = kbf + 8192 * 1024;
  u16* vh  = vbf + 8192 * 1024;
  u16* qwT = vh + 8192 * 1024;         // 4x 1024*1024
  u16* kwT = qwT + 1024 * 1024;
  u16* vwT = kwT + 1024 * 1024;
  u16* woT = vwT + 1024 * 1024;
  u16* vhT    = qbf;                   // reuse after projections
  u16* attn_o = kbf;                   // reuse after projections
  unsigned char* msumb = (unsigned char*)qwT;  // reuse: qwT consumed by gemm#1
  u16* qh = (u16*)d_out;               // park bf16 qh/kh in d_out (exact fit)
  u16* kh = qh + 8192 * 1024;

  cvt_f32_bf16<<<4096, 256, 0, stream>>>(q, qbf, 1048576);
  cvt_f32_bf16<<<4096, 256, 0, stream>>>(k, kbf, 1048576);
  cvt_f32_bf16<<<4096, 256, 0, stream>>>(v, vbf, 1048576);
  wtrans<<<dim3(16, 16, 4), 256, 0, stream>>>(qw_w, kw_w, vw_w, wo,
                                              qwT, kwT, vwT, woT);
  gemm128<<<dim3(8, 64), 256, 0, stream>>>(qbf, qwT, qw_b, qh, 0);
  gemm128<<<dim3(8, 64), 256, 0, stream>>>(kbf, kwT, kw_b, kh, 0);
  gemm128<<<dim3(8, 64), 256, 0, stream>>>(vbf, vwT, vw_b, vh, 0);
  vtrans<<<dim3(32, 64), 256, 0, stream>>>(vh, vhT);
  masksum<<<1024, 256, 0, stream>>>(mask, msumb);  // qwT region free post-gemm#1
  attn_fwd<<<1024, 256, 0, stream>>>(qh, kh, vhT, mask, msumb, attn_o);
  gemm128<<<dim3(8, 64), 256, 0, stream>>>(attn_o, woT, nullptr, d_out, 1);
}

// Round 6
// 324.094 us; speedup vs baseline: 1.4077x; 1.0792x over previous
//
#include <hip/hip_runtime.h>

// Fused MHA: B=4, F=2048, D_HIDDEN=1024, H=16, D=64.
// cvt3(q,k,v) ; wtrans ; 3x proj GEMM ; vtrans ; masksum ; flash attn v3
// (32x32 MFMA, swapped QK^T, permlane32_swap P-redistribution, dbuf single
// barrier, XCD swizzle, defer-max, mask fast-path) ; out GEMM (fp32).
// ws ~75.5 MB; qh/kh (bf16) parked in d_out (exact fit); msum in qwT region.
// FIX vs r5: v_permlane32_swap_b32 operand order (vdst = low-k word; HW swaps
// vdst.hi-lanes <-> vsrc.lo-lanes, per T12 recipe).

typedef unsigned short u16;
typedef __attribute__((ext_vector_type(8))) short short8;
typedef __attribute__((ext_vector_type(4))) float f32x4;
typedef __attribute__((ext_vector_type(16))) float f32x16;

#define SC 0.18033688011112042f          // 0.125 * log2(e)
#define MSC -1.4426950408889634e9f       // -1e9 * log2(e)
#define THR 8.0f                         // defer-max threshold (log2 space)

__device__ __forceinline__ u16 f2bf(float x) {  // RNE fp32->bf16 (finite inputs)
  unsigned int u = __float_as_uint(x);
  u += 0x7FFFu + ((u >> 16) & 1u);
  return (u16)(u >> 16);
}

__device__ __forceinline__ void gload16(const void* g, void* l) {
  __builtin_amdgcn_global_load_lds(
      (const __attribute__((address_space(1))) void*)g,
      (__attribute__((address_space(3))) void*)l, 16, 0, 0);
}

__device__ __forceinline__ uint4 pack8(const u16* t) {
  uint4 o;
  o.x = (unsigned)t[0] | ((unsigned)t[1] << 16);
  o.y = (unsigned)t[2] | ((unsigned)t[3] << 16);
  o.z = (unsigned)t[4] | ((unsigned)t[5] << 16);
  o.w = (unsigned)t[6] | ((unsigned)t[7] << 16);
  return o;
}

__device__ __forceinline__ unsigned cvtpk(float lo, float hi) {
  unsigned r;
  asm("v_cvt_pk_bf16_f32 %0, %1, %2" : "=v"(r) : "v"(lo), "v"(hi));
  return r;
}

// ---------- fp32 -> bf16, 8 elems/thread; blockIdx.y selects q/k/v ----------
__global__ __launch_bounds__(256) void cvt3(const float* __restrict__ q,
                                            const float* __restrict__ k,
                                            const float* __restrict__ v,
                                            u16* __restrict__ dq,
                                            u16* __restrict__ dk,
                                            u16* __restrict__ dv) {
  const float* s;
  u16* d;
  switch (blockIdx.y) {
    case 0: s = q; d = dq; break;
    case 1: s = k; d = dk; break;
    default: s = v; d = dv; break;
  }
  int i = blockIdx.x * 256 + threadIdx.x;
  const float4* sp = (const float4*)s;
  float4 a = sp[2 * i], b = sp[2 * i + 1];
  uint4 o;
  o.x = (unsigned)f2bf(a.x) | ((unsigned)f2bf(a.y) << 16);
  o.y = (unsigned)f2bf(a.z) | ((unsigned)f2bf(a.w) << 16);
  o.z = (unsigned)f2bf(b.x) | ((unsigned)f2bf(b.y) << 16);
  o.w = (unsigned)f2bf(b.z) | ((unsigned)f2bf(b.w) << 16);
  ((uint4*)d)[i] = o;
}

// ---------- mask summary: msum[b][kt][row] = any(mask[b][row][kt*64 .. +63] != 0) ----------
__global__ __launch_bounds__(256) void masksum(const float* __restrict__ mask,
                                               unsigned char* __restrict__ msum) {
  int t = blockIdx.x * 256 + threadIdx.x;   // t = b*65536 + kt*2048 + row
  int row = t & 2047;
  int kt = (t >> 11) & 31;
  int b = t >> 16;
  const float4* p =
      (const float4*)(mask + ((size_t)(b * 2048 + row)) * 2048 + kt * 64);
  unsigned acc = 0;
#pragma unroll
  for (int i = 0; i < 16; i++) {
    float4 f = p[i];
    acc |= __float_as_uint(f.x) | __float_as_uint(f.y) |
           __float_as_uint(f.z) | __float_as_uint(f.w);
  }
  msum[t] = acc ? 1 : 0;
}

// ---------- transpose + cvt: W[1024][1024] fp32 -> WT[1024][1024] bf16 ----------
__global__ __launch_bounds__(256) void wtrans(
    const float* __restrict__ w0, const float* __restrict__ w1,
    const float* __restrict__ w2, const float* __restrict__ w3,
    u16* __restrict__ o0, u16* __restrict__ o1,
    u16* __restrict__ o2, u16* __restrict__ o3) {
  const float* W; u16* O;
  switch (blockIdx.z) {
    case 0: W = w0; O = o0; break;
    case 1: W = w1; O = o1; break;
    case 2: W = w2; O = o2; break;
    default: W = w3; O = o3; break;
  }
  __shared__ u16 T[64][72];
  const int t = threadIdx.x, r = t >> 2, seg = t & 3;
  const int k0 = blockIdx.y * 64, n0 = blockIdx.x * 64;
  const float* src = W + (size_t)(k0 + r) * 1024 + n0 + seg * 16;
#pragma unroll
  for (int jj = 0; jj < 4; jj++) {
    float4 f = ((const float4*)src)[jj];
    T[r][seg * 16 + jj * 4 + 0] = f2bf(f.x);
    T[r][seg * 16 + jj * 4 + 1] = f2bf(f.y);
    T[r][seg * 16 + jj * 4 + 2] = f2bf(f.z);
    T[r][seg * 16 + jj * 4 + 3] = f2bf(f.w);
  }
  __syncthreads();
  u16 tmp[16];
#pragma unroll
  for (int j = 0; j < 16; j++) tmp[j] = T[seg * 16 + j][r];
  u16* dst = O + (size_t)(n0 + r) * 1024 + k0 + seg * 16;
  ((uint4*)dst)[0] = pack8(tmp);
  ((uint4*)dst)[1] = pack8(tmp + 8);
}

// ---------- per-head transpose: vh[8192][1024] -> vhT[(b*16+h)*64 + d][2048] ----------
__global__ __launch_bounds__(256) void vtrans(const u16* __restrict__ vh,
                                              u16* __restrict__ vhT) {
  const int bh = blockIdx.y, f0 = blockIdx.x * 64;
  const int b = bh >> 4, h = bh & 15;
  __shared__ u16 T[64][72];
  const int t = threadIdx.x, r = t >> 2, seg = t & 3;
  const u16* src = vh + (size_t)(b * 2048 + f0 + r) * 1024 + h * 64 + seg * 16;
  uint4 v0 = ((const uint4*)src)[0], v1 = ((const uint4*)src)[1];
  *(uint4*)&T[r][seg * 16] = v0;
  *(uint4*)&T[r][seg * 16 + 8] = v1;
  __syncthreads();
  u16 tmp[16];
#pragma unroll
  for (int j = 0; j < 16; j++) tmp[j] = T[seg * 16 + j][r];
  u16* dst = vhT + (size_t)(bh * 64 + r) * 2048 + f0 + seg * 16;
  ((uint4*)dst)[0] = pack8(tmp);
  ((uint4*)dst)[1] = pack8(tmp + 8);
}

// ---------- 128x128x32 bf16 GEMM: C = A[8192x1024] * Bt[1024x1024]^T ----------
__global__ __launch_bounds__(256) void gemm128(
    const u16* __restrict__ A, const u16* __restrict__ Bt,
    const float* __restrict__ bias, void* __restrict__ Cout, int cfp32) {
  constexpr int K = 1024, N = 1024;
  __shared__ u16 lsA[128 * 32];
  __shared__ u16 lsB[128 * 32];
  const int tid = threadIdx.x;
  const int w = tid >> 6, lane = tid & 63;
  const int l15 = lane & 15, lg = lane >> 4;
  const int m0 = blockIdx.y << 7, n0 = blockIdx.x << 7;
  const int wr = w >> 1, wc = w & 1;

  f32x4 acc[4][4];
#pragma unroll
  for (int i = 0; i < 4; i++)
#pragma unroll
    for (int j = 0; j < 4; j++) acc[i][j] = f32x4{0.f, 0.f, 0.f, 0.f};

  const u16* As = A + (size_t)(m0 + w * 32 + (lane >> 2)) * K + (lane & 3) * 8;
  const u16* Bs = Bt + (size_t)(n0 + w * 32 + (lane >> 2)) * K + (lane & 3) * 8;
  u16* lA = &lsA[(w * 32) * 32];
  u16* lB = &lsB[(w * 32) * 32];

  for (int k0 = 0; k0 < K; k0 += 32) {
    gload16(As + k0, lA);
    gload16(As + 16 * K + k0, lA + 16 * 32);
    gload16(Bs + k0, lB);
    gload16(Bs + 16 * K + k0, lB + 16 * 32);
    __syncthreads();
    short8 af[4], bfv[4];
#pragma unroll
    for (int mi = 0; mi < 4; mi++)
      af[mi] = *(const short8*)&lsA[(wr * 64 + mi * 16 + l15) * 32 + lg * 8];
#pragma unroll
    for (int nj = 0; nj < 4; nj++)
      bfv[nj] = *(const short8*)&lsB[(wc * 64 + nj * 16 + l15) * 32 + lg * 8];
#pragma unroll
    for (int mi = 0; mi < 4; mi++)
#pragma unroll
      for (int nj = 0; nj < 4; nj++)
        acc[mi][nj] = __builtin_amdgcn_mfma_f32_16x16x32_bf16(af[mi], bfv[nj],
                                                              acc[mi][nj], 0, 0, 0);
    __syncthreads();
  }

  const int crow = m0 + wr * 64 + lg * 4;
  const int ccol = n0 + wc * 64 + l15;
  if (cfp32) {
    float* C = (float*)Cout;
#pragma unroll
    for (int nj = 0; nj < 4; nj++)
#pragma unroll
      for (int mi = 0; mi < 4; mi++)
#pragma unroll
        for (int r = 0; r < 4; r++)
          C[(size_t)(crow + mi * 16 + r) * N + ccol + nj * 16] = acc[mi][nj][r];
  } else {
    u16* C = (u16*)Cout;
#pragma unroll
    for (int nj = 0; nj < 4; nj++) {
      float bv = bias[ccol + nj * 16];
#pragma unroll
      for (int mi = 0; mi < 4; mi++)
#pragma unroll
        for (int r = 0; r < 4; r++)
          C[(size_t)(crow + mi * 16 + r) * N + ccol + nj * 16] =
              f2bf(acc[mi][nj][r] + bv);
    }
  }
}

// ---------- flash attention v3: 32x32 MFMA, permlane P-redistribution ----------
// grid 1024 (XCD-swizzled): virt blk = ((b*16+h)*16 + qtile).
// 4 waves; wave owns 32 q-rows (q = lane&31); KTILE=64, dbuf, 1 barrier/tile.
__global__ __launch_bounds__(256, 4) void attn_fwd(
    const u16* __restrict__ qh, const u16* __restrict__ kh,
    const u16* __restrict__ vhT, const float* __restrict__ mask,
    const unsigned char* __restrict__ msum, u16* __restrict__ aout) {
  __shared__ u16 Kls[2][64][72];   // [buf][krow][d]
  __shared__ u16 Vls[2][64][72];   // [buf][d][kcol] (V^T)

  const int tid = threadIdx.x;
  const int w = tid >> 6, lane = tid & 63;
  const int l31 = lane & 31, hi = lane >> 5;
  // XCD swizzle: 16 q-tiles of a head land on the same XCD (K/V L2 reuse)
  const int blk = ((blockIdx.x & 7) << 7) | (blockIdx.x >> 3);
  const int qt = blk & 15, bh = blk >> 4, h = bh & 15, b = bh >> 4;
  const int frow = qt * 128 + w * 32;            // q row within batch b
  const size_t qrow0 = (size_t)b * 2048 + frow;  // q row in [8192]

  // Q B-frag: lane holds q-row = l31, d = ds*16 + hi*8 + j
  short8 qf[4];
#pragma unroll
  for (int ds = 0; ds < 4; ds++)
    qf[ds] = *(const short8*)&qh[(qrow0 + l31) * 1024 + h * 64 + ds * 16 + hi * 8];

  f32x16 oacc[2];
#pragma unroll
  for (int i = 0; i < 16; i++) { oacc[0][i] = 0.f; oacc[1][i] = 0.f; }
  float m_run = -1e30f, l_run = 0.f;  // per q = l31, log2-scaled space

  const int sr = tid >> 2, seg = tid & 3;  // staging: row, 16-elem segment
  const u16* Ksrc = kh + ((size_t)b * 2048 + sr) * 1024 + h * 64 + seg * 16;
  const u16* Vsrc = vhT + ((size_t)bh * 64 + sr) * 2048 + seg * 16;
  const unsigned char* msrow = msum + (size_t)b * 65536 + frow + l31;

  uint4 ka0, ka1, va0, va1;
  unsigned char mb, mbn;
  {  // prologue: tile 0 -> LDS[0]; prefetch tile 1 into regs
    const uint4* kp = (const uint4*)Ksrc;
    uint4 x0 = kp[0], x1 = kp[1];
    const uint4* vp = (const uint4*)Vsrc;
    uint4 y0 = vp[0], y1 = vp[1];
    *(uint4*)&Kls[0][sr][seg * 16] = x0;
    *(uint4*)&Kls[0][sr][seg * 16 + 8] = x1;
    *(uint4*)&Vls[0][sr][seg * 16] = y0;
    *(uint4*)&Vls[0][sr][seg * 16 + 8] = y1;
    kp = (const uint4*)(Ksrc + 64 * 1024);
    ka0 = kp[0]; ka1 = kp[1];
    vp = (const uint4*)(Vsrc + 64);
    va0 = vp[0]; va1 = vp[1];
    mb = msrow[0];
    mbn = msrow[2048];
  }
  __syncthreads();

  for (int kt = 0; kt < 32; kt++) {
    const int cur = kt & 1;
    const int k0 = kt * 64;
    const int mflag = __any((int)mb);
    mb = mbn;

    // write prefetched tile kt+1 -> LDS[cur^1]; issue loads for tile kt+2
    if (kt < 31) {
      *(uint4*)&Kls[cur ^ 1][sr][seg * 16] = ka0;
      *(uint4*)&Kls[cur ^ 1][sr][seg * 16 + 8] = ka1;
      *(uint4*)&Vls[cur ^ 1][sr][seg * 16] = va0;
      *(uint4*)&Vls[cur ^ 1][sr][seg * 16 + 8] = va1;
    }
    if (kt < 30) {
      const uint4* kp = (const uint4*)(Ksrc + (size_t)(kt + 2) * 64 * 1024);
      ka0 = kp[0]; ka1 = kp[1];
      const uint4* vp = (const uint4*)(Vsrc + (kt + 2) * 64);
      va0 = vp[0]; va1 = vp[1];
      mbn = msrow[(size_t)(kt + 2) * 2048];
    }

    // ---- S^T = K * Q^T : sacc[kb], k = kb*32 + (reg&3)+8(reg>>2)+4hi, q = l31 ----
    f32x16 sacc[2];
#pragma unroll
    for (int i = 0; i < 16; i++) { sacc[0][i] = 0.f; sacc[1][i] = 0.f; }
#pragma unroll
    for (int kb = 0; kb < 2; kb++) {
      short8 kf[4];
#pragma unroll
      for (int ds = 0; ds < 4; ds++)
        kf[ds] = *(const short8*)&Kls[cur][kb * 32 + l31][ds * 16 + hi * 8];
      __builtin_amdgcn_s_setprio(1);
#pragma unroll
      for (int ds = 0; ds < 4; ds++)
        sacc[kb] = __builtin_amdgcn_mfma_f32_32x32x16_bf16(kf[ds], qf[ds],
                                                           sacc[kb], 0, 0, 0);
      __builtin_amdgcn_s_setprio(0);
    }

    // ---- softmax: lane owns q = l31, 32 k-scores in-lane ----
    float AS = SC;
    float mx[16];
#pragma unroll
    for (int r = 0; r < 16; r++) mx[r] = fmaxf(sacc[0][r], sacc[1][r]);
#pragma unroll
    for (int s = 8; s >= 1; s >>= 1)
#pragma unroll
      for (int r = 0; r < s; r++) mx[r] = fmaxf(mx[r], mx[r + s]);
    float tm = mx[0] * SC;
    if (mflag) {  // rare: apply additive mask (pre-scaled), redo max
      const size_t mrow = ((size_t)b * 2048 + frow + l31) * 2048 + (size_t)k0;
#pragma unroll
      for (int kb = 0; kb < 2; kb++)
#pragma unroll
        for (int r = 0; r < 16; r++) {
          float mv = mask[mrow + kb * 32 + (r & 3) + 8 * (r >> 2) + 4 * hi];
          sacc[kb][r] = fmaf(mv, MSC, sacc[kb][r] * SC);
        }
#pragma unroll
      for (int r = 0; r < 16; r++) mx[r] = fmaxf(sacc[0][r], sacc[1][r]);
#pragma unroll
      for (int s = 8; s >= 1; s >>= 1)
#pragma unroll
        for (int r = 0; r < s; r++) mx[r] = fmaxf(mx[r], mx[r + s]);
      tm = mx[0];
      AS = 1.f;
    }
    tm = fmaxf(tm, __shfl_xor(tm, 32, 64));

    if (!__all(tm <= m_run + THR)) {  // defer-max: rescale only on real growth
      float mnew = fmaxf(m_run, tm);
      float al = exp2f(m_run - mnew);
      m_run = mnew;
      l_run *= al;
#pragma unroll
      for (int r = 0; r < 16; r++) {
        float alr = __shfl(al, (r & 3) + 8 * (r >> 2) + 4 * hi, 64);
        oacc[0][r] *= alr;
        oacc[1][r] *= alr;
      }
    }
    const float mm = m_run;

    // exp + sum + pack + permlane32_swap -> PV A-frag words
    // vdst = low-k word (ye), vsrc = k+8 word (xo): HW swaps vdst.hi <-> vsrc.lo
    // -> ye_new = {lo: P[k..k+1](hi0), hi: P[k+8..k+9](hi0-data)} = A-frag word.
    float rsp = 0.f, rsq = 0.f;
    unsigned pw[16];
#pragma unroll
    for (int kb = 0; kb < 2; kb++)
#pragma unroll
      for (int jp = 0; jp < 2; jp++) {
        float e[8];
#pragma unroll
        for (int t = 0; t < 8; t++)
          e[t] = exp2f(fmaf(sacc[kb][8 * jp + t], AS, -mm));
        rsp += (e[0] + e[1]) + (e[2] + e[3]);
        rsq += (e[4] + e[5]) + (e[6] + e[7]);
        unsigned ye0 = cvtpk(e[0], e[1]);
        unsigned ye1 = cvtpk(e[2], e[3]);
        unsigned xo0 = cvtpk(e[4], e[5]);
        unsigned xo1 = cvtpk(e[6], e[7]);
        asm volatile("v_permlane32_swap_b32 %0, %1" : "+v"(ye0), "+v"(xo0));
        asm volatile("v_permlane32_swap_b32 %0, %1" : "+v"(ye1), "+v"(xo1));
        const int kk = kb * 2 + jp;
        pw[kk * 4 + 0] = ye0;
        pw[kk * 4 + 1] = ye1;
        pw[kk * 4 + 2] = xo0;
        pw[kk * 4 + 3] = xo1;
      }
    float rs = rsp + rsq;
    rs += __shfl_xor(rs, 32, 64);
    l_run += rs;

    // ---- O += P * V ----
#pragma unroll
    for (int dn = 0; dn < 2; dn++) {
      short8 vf[4];
#pragma unroll
      for (int kk = 0; kk < 4; kk++)
        vf[kk] = *(const short8*)&Vls[cur][dn * 32 + l31][kk * 16 + hi * 8];
      __builtin_amdgcn_s_setprio(1);
#pragma unroll
      for (int kk = 0; kk < 4; kk++) {
        uint4 t4 = {pw[kk * 4 + 0], pw[kk * 4 + 1], pw[kk * 4 + 2], pw[kk * 4 + 3]};
        oacc[dn] = __builtin_amdgcn_mfma_f32_32x32x16_bf16(
            *(short8*)&t4, vf[kk], oacc[dn], 0, 0, 0);
      }
      __builtin_amdgcn_s_setprio(0);
    }

    __syncthreads();
  }

  // ---- epilogue: O / l ----
  float inv = 1.0f / l_run;
#pragma unroll
  for (int r = 0; r < 16; r++) {
    const int qr = (r & 3) + 8 * (r >> 2) + 4 * hi;
    float invr = __shfl(inv, qr, 64);
    aout[(qrow0 + qr) * 1024 + h * 64 + l31] = f2bf(oacc[0][r] * invr);
    aout[(qrow0 + qr) * 1024 + h * 64 + 32 + l31] = f2bf(oacc[1][r] * invr);
  }
}

extern "C" void kernel_launch(void* const* d_in, const int* in_sizes, int n_in,
                              void* d_out, int out_size, void* d_ws, size_t ws_size,
                              hipStream_t stream) {
  (void)in_sizes; (void)n_in; (void)out_size; (void)ws_size;
  const float* q    = (const float*)d_in[0];
  const float* k    = (const float*)d_in[1];
  const float* v    = (const float*)d_in[2];
  const float* mask = (const float*)d_in[3];
  const float* qw_w = (const float*)d_in[4];
  const float* qw_b = (const float*)d_in[5];
  const float* kw_w = (const float*)d_in[6];
  const float* kw_b = (const float*)d_in[7];
  const float* vw_w = (const float*)d_in[8];
  const float* vw_b = (const float*)d_in[9];
  const float* wo   = (const float*)d_in[10];

  // workspace layout (u16 elems); total 75.5 MB
  u16* qbf = (u16*)d_ws;               // 8192*1024
  u16* kbf = qbf + 8192 * 1024;
  u16* vbf = kbf + 8192 * 1024;
  u16* vh  = vbf + 8192 * 1024;
  u16* qwT = vh + 8192 * 1024;         // 4x 1024*1024
  u16* kwT = qwT + 1024 * 1024;
  u16* vwT = kwT + 1024 * 1024;
  u16* woT = vwT + 1024 * 1024;
  u16* vhT    = qbf;                   // reuse after projections
  u16* attn_o = kbf;                   // reuse after projections
  unsigned char* msumb = (unsigned char*)qwT;  // reuse: qwT consumed by gemm#1
  u16* qh = (u16*)d_out;               // park bf16 qh/kh in d_out (exact fit)
  u16* kh = qh + 8192 * 1024;

  cvt3<<<dim3(4096, 3), 256, 0, stream>>>(q, k, v, qbf, kbf, vbf);
  wtrans<<<dim3(16, 16, 4), 256, 0, stream>>>(qw_w, kw_w, vw_w, wo,
                                              qwT, kwT, vwT, woT);
  gemm128<<<dim3(8, 64), 256, 0, stream>>>(qbf, qwT, qw_b, qh, 0);
  gemm128<<<dim3(8, 64), 256, 0, stream>>>(kbf, kwT, kw_b, kh, 0);
  gemm128<<<dim3(8, 64), 256, 0, stream>>>(vbf, vwT, vw_b, vh, 0);
  vtrans<<<dim3(32, 64), 256, 0, stream>>>(vh, vhT);
  masksum<<<1024, 256, 0, stream>>>(mask, msumb);  // qwT free post-gemm#1
  attn_fwd<<<1024, 256, 0, stream>>>(qh, kh, vhT, mask, msumb, attn_o);
  gemm128<<<dim3(8, 64), 256, 0, stream>>>(attn_o, woT, nullptr, d_out, 1);
}